// Round 3
// 377.445 us; speedup vs baseline: 1.0415x; 1.0415x over previous
//
#include <hip/hip_runtime.h>
#include <math.h>

#define NPIX 16384      // H*W
#define DIMC 256        // dim
#define BATCH 8
#define HEADS 4
#define DHEAD 32
#define HID 128         // HEADS*DHEAD
#define OQKV 384        // 3*HID
#define EPS 1e-5f
#define SCALE 0.17677669529663687f  // 32^-0.5

typedef _Float16 f16x8 __attribute__((ext_vector_type(8)));
typedef float f32x4 __attribute__((ext_vector_type(4)));

// async global->LDS, 16B per lane (dest must be wave-uniform base + lane*16)
__device__ inline void gl_lds16(const void* g, void* l) {
    __builtin_amdgcn_global_load_lds(
        (const __attribute__((address_space(1))) unsigned*)g,
        (__attribute__((address_space(3))) unsigned*)l, 16, 0, 0);
}

// ---------------------------------------------------------------------------
// weights fp32->fp16 + zero atomic accumulators (ctx_raw+ksum+lnacc = 37888)
__global__ __launch_bounds__(256) void prep_kernel(
    const float* __restrict__ qkv_w, const float* __restrict__ conv_w,
    _Float16* __restrict__ wh, _Float16* __restrict__ ch, float* __restrict__ zbuf)
{
    int i = blockIdx.x * 256 + threadIdx.x;       // 0..131071
    if (i < 98304) wh[i] = (_Float16)qkv_w[i];
    else           ch[i - 98304] = (_Float16)conv_w[i - 98304];
    if (i < 37888) zbuf[i] = 0.f;
}

// ---------------------------------------------------------------------------
// Fused transpose + QKV GEMM: C[b][o][n] = sum_c W[o][c] * x[b][c][n]
// A (wh) is fp16 k-contiguous, staged via global_load_lds as before.
// B is the raw fp32 x in [c][n] layout: the 32x128 fp32 tile is staged
// LINEARLY via global_load_lds (lane order already matches), and the
// transpose+fp16 convert happens at fragment-read time (8 strided b32
// reads per fragment). Bank conflicts of the strided read are reduced
// from 4-way to free 2-way by XOR-swizzling the n index per 8-row c
// group — applied on the GLOBAL source address (linear LDS dest can't
// be swizzled) and identically on the read side.
__global__ __launch_bounds__(256) void gemm_qkv(
    const _Float16* __restrict__ A,    // [384][256] fp16
    const float* __restrict__ X,       // [b][256][16384] fp32
    _Float16* __restrict__ Cm)         // [b][384][16384]
{
    __shared__ _Float16 smem[16384];   // As 8KB | Xs 16KB fp32 ; reused as Cs 32KB
    _Float16* As = smem;
    float* Xs = (float*)(smem + 4096);
    const int t  = threadIdx.x;
    const int b  = blockIdx.x;
    const int m0 = blockIdx.y * 128;
    const int n0 = blockIdx.z * 128;
    const float* Xb = X + (long)b * DIMC * NPIX;
    const int w = t >> 6, lane = t & 63;
    const int q = lane >> 4, l16 = lane & 15;
    const int mw = (w >> 1) * 64, nw = (w & 1) * 64;
    const int swzq = ((q & 1) << 4) | ((q >> 1) << 2);   // read-side n XOR

    f32x4 acc[4][4] = {};

    for (int k0 = 0; k0 < DIMC; k0 += 32) {
        // A tile: 128 rows x 32 k fp16 = 8KB, 2 loads/thread
        #pragma unroll
        for (int is = 0; is < 2; is++) {
            int idx = is * 256 + t;               // 0..511
            int row = idx >> 2, kc = (idx & 3) * 8;
            gl_lds16(&A[(long)(m0 + row) * DIMC + k0 + kc], &As[idx * 8]);
        }
        // X tile: 32 c x 128 n fp32 = 16KB, 4 loads/thread, source-swizzled
        #pragma unroll
        for (int is = 0; is < 4; is++) {
            int idx = is * 256 + t;               // 0..1023
            int c = idx >> 5, f4 = (idx & 31) * 4;
            int qc = c >> 3;
            int sw = ((qc & 1) << 4) | ((qc >> 1) << 2);
            gl_lds16(&Xb[(long)(k0 + c) * NPIX + n0 + (f4 ^ sw)], &Xs[c * 128 + f4]);
        }
        __syncthreads();
        f16x8 af[4], bf[4];
        #pragma unroll
        for (int i = 0; i < 4; i++)
            af[i] = *(const f16x8*)&As[(mw + i * 16 + l16) * 32 + q * 8];
        #pragma unroll
        for (int i = 0; i < 4; i++) {
            int n = nw + i * 16 + l16;
            const float* xp = &Xs[q * 8 * 128 + (n ^ swzq)];
            #pragma unroll
            for (int j = 0; j < 8; j++) bf[i][j] = (_Float16)xp[j * 128];
        }
        #pragma unroll
        for (int i = 0; i < 4; i++)
            #pragma unroll
            for (int j = 0; j < 4; j++)
                acc[i][j] = __builtin_amdgcn_mfma_f32_16x16x32_f16(af[i], bf[j], acc[i][j], 0, 0, 0);
        __syncthreads();
    }

    // ---- epilogue: acc -> swizzled LDS -> coalesced global ----
    _Float16* Cs = smem;
    #pragma unroll
    for (int i = 0; i < 4; i++) {
        #pragma unroll
        for (int j = 0; j < 4; j++) {
            #pragma unroll
            for (int r = 0; r < 4; r++) {
                int row = mw + i * 16 + q * 4 + r;
                int col = nw + j * 16 + l16;
                Cs[row * 128 + (col ^ ((row & 15) << 3))] = (_Float16)acc[i][j][r];
            }
        }
    }
    __syncthreads();
    _Float16* Cb = Cm + (long)b * ((long)OQKV * NPIX);
    #pragma unroll
    for (int it = 0; it < 8; it++) {
        int u = it * 256 + t;                  // 0..2047
        int row = u >> 4, cg = u & 15;
        f16x8 v8 = *(const f16x8*)&Cs[row * 128 + ((cg * 8) ^ ((row & 15) << 3))];
        *(f16x8*)&Cb[(long)(m0 + row) * NPIX + n0 + cg * 8] = v8;
    }
}

// ---------------------------------------------------------------------------
// MFMA fp16 GEMM: C[b][m][n] = sum_k A[m][k] * B[b][n][k]   (both k-contiguous)
// 128x128 tile, BK=32, 256 threads (4 waves, 64x64 each), 16x16x32 MFMA.
// grid (b=8, m-blocks, n-blocks=128): same-B m-blocks land on the same XCD
// 8 dispatches apart -> B-tile L2 reuse.
// Epilogue: XOR-swizzled LDS C-tile (reuses staging LDS) -> coalesced f16x8
// stores. EPI=1: also accumulate per-row sum/sumsq into lnacc via atomics.
template<int K, int EPI>
__global__ __launch_bounds__(256) void gemm_h(
    const _Float16* __restrict__ A,    // [M][K]
    const _Float16* __restrict__ Bm,   // [b][N][K]
    _Float16* __restrict__ Cm,         // [b][M][NPIX]
    long bsB, long bsC, float* __restrict__ lnacc)
{
    __shared__ _Float16 smem[16384];   // As 8KB | Bs 8KB ; reused as Cs 32KB
    _Float16* As = smem;
    _Float16* Bs = smem + 4096;
    const int t  = threadIdx.x;
    const int b  = blockIdx.x;
    const int m0 = blockIdx.y * 128;
    const int n0 = blockIdx.z * 128;
    const _Float16* Bb = Bm + (long)b * bsB;
    const int w = t >> 6, lane = t & 63;
    const int q = lane >> 4, l16 = lane & 15;
    const int mw = (w >> 1) * 64, nw = (w & 1) * 64;

    f32x4 acc[4][4] = {};

    for (int k0 = 0; k0 < K; k0 += 32) {
        #pragma unroll
        for (int is = 0; is < 2; is++) {
            int idx = is * 256 + t;               // 0..511
            int row = idx >> 2, kc = (idx & 3) * 8;
            gl_lds16(&A [(long)(m0 + row) * K + k0 + kc], &As[idx * 8]);
            gl_lds16(&Bb[(long)(n0 + row) * K + k0 + kc], &Bs[idx * 8]);
        }
        __syncthreads();
        f16x8 af[4], bf[4];
        #pragma unroll
        for (int i = 0; i < 4; i++) {
            af[i] = *(const f16x8*)&As[(mw + i * 16 + l16) * 32 + q * 8];
            bf[i] = *(const f16x8*)&Bs[(nw + i * 16 + l16) * 32 + q * 8];
        }
        #pragma unroll
        for (int i = 0; i < 4; i++)
            #pragma unroll
            for (int j = 0; j < 4; j++)
                acc[i][j] = __builtin_amdgcn_mfma_f32_16x16x32_f16(af[i], bf[j], acc[i][j], 0, 0, 0);
        __syncthreads();
    }

    // ---- epilogue: acc -> swizzled LDS -> coalesced global ----
    _Float16* Cs = smem;
    #pragma unroll
    for (int i = 0; i < 4; i++) {
        #pragma unroll
        for (int j = 0; j < 4; j++) {
            #pragma unroll
            for (int r = 0; r < 4; r++) {
                int row = mw + i * 16 + q * 4 + r;
                int col = nw + j * 16 + l16;
                Cs[row * 128 + (col ^ ((row & 15) << 3))] = (_Float16)acc[i][j][r];
            }
        }
    }
    __syncthreads();
    _Float16* Cb = Cm + (long)b * bsC;
    #pragma unroll
    for (int it = 0; it < 8; it++) {
        int u = it * 256 + t;                  // 0..2047
        int row = u >> 4, cg = u & 15;
        f16x8 v8 = *(const f16x8*)&Cs[row * 128 + ((cg * 8) ^ ((row & 15) << 3))];
        *(f16x8*)&Cb[(long)(m0 + row) * NPIX + n0 + cg * 8] = v8;
        if (EPI) {
            float s = 0.f, sq = 0.f;
            #pragma unroll
            for (int k = 0; k < 8; k++) { float f = (float)v8[k]; s += f; sq += f * f; }
            #pragma unroll
            for (int off = 8; off > 0; off >>= 1) {
                s  += __shfl_down(s,  off, 16);
                sq += __shfl_down(sq, off, 16);
            }
            if ((t & 15) == 0) {
                int rg = b * DIMC + m0 + row;
                atomicAdd(&lnacc[rg * 2],     s);
                atomicAdd(&lnacc[rg * 2 + 1], sq);
            }
        }
    }
}

// ---------------------------------------------------------------------------
// MFMA context: ctx_raw[bh][d][e] += sum_n exp(k[d,n]) * v[e,n]
//               ksum[bh][d]       += sum_n exp(k[d,n])
// No max-subtraction: k ~ N(0,1), exp safe in fp32; softmax shift-invariant.
// grid (8 chunks, 32 bh), 4 waves/block each covering 512 n.
__global__ __launch_bounds__(256) void ctx_mfma(const _Float16* __restrict__ qkvh,
    float* __restrict__ ctx_raw, float* __restrict__ ksum)
{
    __shared__ float cbuf[4][1024];
    int t = threadIdx.x;
    int w = t >> 6, lane = t & 63;
    int q = lane >> 4, l16 = lane & 15;
    int bh = blockIdx.y, b = bh >> 2, h = bh & 3;
    const _Float16* kb = qkvh + ((long)b * OQKV + HID + h * DHEAD) * NPIX;
    const _Float16* vb = qkvh + ((long)b * OQKV + 2 * HID + h * DHEAD) * NPIX;
    long n0 = (long)blockIdx.x * 2048 + w * 512 + q * 8;

    f32x4 c00 = {}, c01 = {}, c10 = {}, c11 = {};
    float ks0 = 0.f, ks1 = 0.f;

    for (int s = 0; s < 16; s++) {
        long n = n0 + s * 32;
        f16x8 kf0 = *(const f16x8*)&kb[(long)l16 * NPIX + n];
        f16x8 kf1 = *(const f16x8*)&kb[(long)(16 + l16) * NPIX + n];
        f16x8 vf0 = *(const f16x8*)&vb[(long)l16 * NPIX + n];
        f16x8 vf1 = *(const f16x8*)&vb[(long)(16 + l16) * NPIX + n];
        f16x8 e0, e1;
        #pragma unroll
        for (int j = 0; j < 8; j++) {
            float ea = __expf((float)kf0[j]); e0[j] = (_Float16)ea; ks0 += ea;
            float eb = __expf((float)kf1[j]); e1[j] = (_Float16)eb; ks1 += eb;
        }
        c00 = __builtin_amdgcn_mfma_f32_16x16x32_f16(e0, vf0, c00, 0, 0, 0);
        c01 = __builtin_amdgcn_mfma_f32_16x16x32_f16(e0, vf1, c01, 0, 0, 0);
        c10 = __builtin_amdgcn_mfma_f32_16x16x32_f16(e1, vf0, c10, 0, 0, 0);
        c11 = __builtin_amdgcn_mfma_f32_16x16x32_f16(e1, vf1, c11, 0, 0, 0);
    }

    // ksum: reduce across q-groups (lanes l16, +16, +32, +48)
    ks0 += __shfl_down(ks0, 32); ks0 += __shfl_down(ks0, 16);
    ks1 += __shfl_down(ks1, 32); ks1 += __shfl_down(ks1, 16);
    if (lane < 16) {
        atomicAdd(&ksum[bh * DHEAD + l16],      ks0);
        atomicAdd(&ksum[bh * DHEAD + 16 + l16], ks1);
    }

    // ctx: combine 4 waves via LDS, one atomicAdd per entry
    float* cb = cbuf[w];
    #pragma unroll
    for (int r = 0; r < 4; r++) {
        cb[(q * 4 + r) * 32 + l16]            = c00[r];
        cb[(q * 4 + r) * 32 + 16 + l16]       = c01[r];
        cb[(16 + q * 4 + r) * 32 + l16]       = c10[r];
        cb[(16 + q * 4 + r) * 32 + 16 + l16]  = c11[r];
    }
    __syncthreads();
    #pragma unroll
    for (int ii = 0; ii < 4; ii++) {
        int idx = ii * 256 + t;
        float s = cbuf[0][idx] + cbuf[1][idx] + cbuf[2][idx] + cbuf[3][idx];
        atomicAdd(&ctx_raw[(long)bh * 1024 + idx], s);
    }
}

// ---------------------------------------------------------------------------
// q-softmax + out' = N*out = (SCALE*ctx_raw/ksum) @ qsm, written into the
// dead v-region as [b][n][e] fp16 (k-contiguous for the conv GEMM).
__global__ __launch_bounds__(256) void outq_h(_Float16* __restrict__ qkvh,
    const float* __restrict__ ctx_raw, const float* __restrict__ ksum)
{
    __shared__ float ctx_t[4][32][32];   // [h][e][d]
    int tid = threadIdx.x;
    int n = blockIdx.x * 256 + tid;
    int b = blockIdx.y;
    #pragma unroll
    for (int i = 0; i < 16; i++) {
        int idx = i * 256 + tid;           // 0..4095
        int h = idx >> 10, de = idx & 1023;
        int d = de >> 5, e = de & 31;
        float s = ksum[(b * 4 + h) * DHEAD + d];
        ctx_t[h][e][d] = SCALE * ctx_raw[(long)(b * 4 + h) * 1024 + de] / s;
    }
    __syncthreads();
    _Float16* ob = qkvh + ((long)b * OQKV + 2 * HID) * NPIX + (long)n * HID;
    for (int h = 0; h < 4; h++) {
        const _Float16* qb = qkvh + ((long)b * OQKV + h * DHEAD) * NPIX + n;
        float qv[32];
        float mx = -1e30f;
        #pragma unroll
        for (int e = 0; e < 32; e++) { qv[e] = (float)qb[(long)e * NPIX]; mx = fmaxf(mx, qv[e]); }
        float s = 0.f;
        #pragma unroll
        for (int e = 0; e < 32; e++) { qv[e] = __expf(qv[e] - mx); s += qv[e]; }
        float qs = 1.f / s;
        float4 o4[8];
        #pragma unroll
        for (int j = 0; j < 8; j++) o4[j] = make_float4(0,0,0,0);
        #pragma unroll 8
        for (int e = 0; e < 32; e++) {
            float qe = qv[e] * qs;
            #pragma unroll
            for (int j = 0; j < 8; j++) {
                float4 c = *(const float4*)&ctx_t[h][e][j * 4];
                o4[j].x += c.x * qe; o4[j].y += c.y * qe;
                o4[j].z += c.z * qe; o4[j].w += c.w * qe;
            }
        }
        #pragma unroll
        for (int j = 0; j < 4; j++) {
            f16x8 pk;
            float4 a = o4[j * 2], bb = o4[j * 2 + 1];
            pk[0] = (_Float16)a.x;  pk[1] = (_Float16)a.y;
            pk[2] = (_Float16)a.z;  pk[3] = (_Float16)a.w;
            pk[4] = (_Float16)bb.x; pk[5] = (_Float16)bb.y;
            pk[6] = (_Float16)bb.z; pk[7] = (_Float16)bb.w;
            *(f16x8*)&ob[h * DHEAD + j * 8] = pk;
        }
    }
}

// ---------------------------------------------------------------------------
// finalize LN coefficients from the fused sums (y' = N*y scale)
__global__ __launch_bounds__(256) void ln_finalize(const float* __restrict__ lnacc,
    const float* __restrict__ gamma, const float* __restrict__ beta,
    float* __restrict__ mv)
{
    int row = blockIdx.x * 256 + threadIdx.x;     // 0..2047
    float s = lnacc[row * 2], sq = lnacc[row * 2 + 1];
    float meanp = s * (1.f / NPIX);
    float varp  = fmaxf(sq * (1.f / NPIX) - meanp * meanp, 0.f);
    float rinv  = rsqrtf(varp * (1.f / ((float)NPIX * (float)NPIX)) + EPS);
    int c = row & 255;
    float g = rinv * gamma[c];
    mv[row * 2]     = g * (1.f / NPIX);
    mv[row * 2 + 1] = beta[c] - meanp * (1.f / NPIX) * g;
}

// ---------------------------------------------------------------------------
// out = y' * a + be   (fp16 in, fp32 out)
__global__ __launch_bounds__(256) void ln_apply(const _Float16* __restrict__ yh,
    const float* __restrict__ mv, float* __restrict__ out)
{
    long i8 = (long)blockIdx.x * 256 + threadIdx.x;   // f16x8 index
    int row = (int)(i8 >> 11);                        // 2048 vec8 per row
    float a = mv[row * 2], be = mv[row * 2 + 1];
    f16x8 v = *(const f16x8*)&yh[i8 * 8];
    float4 o1, o2;
    o1.x = (float)v[0] * a + be; o1.y = (float)v[1] * a + be;
    o1.z = (float)v[2] * a + be; o1.w = (float)v[3] * a + be;
    o2.x = (float)v[4] * a + be; o2.y = (float)v[5] * a + be;
    o2.z = (float)v[6] * a + be; o2.w = (float)v[7] * a + be;
    *(float4*)&out[i8 * 8]     = o1;
    *(float4*)&out[i8 * 8 + 4] = o2;
}

// ---------------------------------------------------------------------------
extern "C" void kernel_launch(void* const* d_in, const int* in_sizes, int n_in,
                              void* d_out, int out_size, void* d_ws, size_t ws_size,
                              hipStream_t stream)
{
    const float* x      = (const float*)d_in[0];
    const float* qkv_w  = (const float*)d_in[1];
    const float* conv_w = (const float*)d_in[2];
    const float* gamma  = (const float*)d_in[4];
    const float* beta   = (const float*)d_in[5];
    float* out = (float*)d_out;

    _Float16* yh   = (_Float16*)d_ws;                 // 33,554,432 h (conv output)
    _Float16* qkvh = yh + 33554432;                   // 50,331,648 h
    _Float16* wh   = qkvh + 50331648;                 // 98,304 h
    _Float16* ch   = wh + 98304;                      // 32,768 h
    float* ctx_raw = (float*)(ch + 32768);            // 32,768
    float* ksum    = ctx_raw + 32768;                 // 1,024
    float* lnacc   = ksum + 1024;                     // 4,096
    float* mv      = lnacc + 4096;                    // 4,096

    prep_kernel<<<512, 256, 0, stream>>>(qkv_w, conv_w, wh, ch, ctx_raw);
    gemm_qkv<<<dim3(BATCH, 3, 128), 256, 0, stream>>>(wh, x, qkvh);
    ctx_mfma<<<dim3(8, 32), 256, 0, stream>>>(qkvh, ctx_raw, ksum);
    outq_h<<<dim3(64, BATCH), 256, 0, stream>>>(qkvh, ctx_raw, ksum);
    gemm_h<128, 1><<<dim3(BATCH, 2, 128), 256, 0, stream>>>(
        ch, qkvh + (long)2 * HID * NPIX, yh, (long)OQKV * NPIX, (long)DIMC * NPIX, lnacc);
    ln_finalize<<<8, 256, 0, stream>>>(lnacc, gamma, beta, mv);
    ln_apply<<<16384, 256, 0, stream>>>(yh, mv, out);
}

// Round 4
// 374.918 us; speedup vs baseline: 1.0485x; 1.0067x over previous
//
#include <hip/hip_runtime.h>
#include <math.h>

#define NPIX 16384      // H*W
#define DIMC 256        // dim
#define BATCH 8
#define HEADS 4
#define DHEAD 32
#define HID 128         // HEADS*DHEAD
#define OQKV 384        // 3*HID
#define EPS 1e-5f
#define SCALE 0.17677669529663687f  // 32^-0.5

typedef _Float16 f16x8 __attribute__((ext_vector_type(8)));
typedef _Float16 f16x4 __attribute__((ext_vector_type(4)));
typedef float f32x4 __attribute__((ext_vector_type(4)));

// async global->LDS, 16B per lane (dest must be wave-uniform base + lane*16)
__device__ inline void gl_lds16(const void* g, void* l) {
    __builtin_amdgcn_global_load_lds(
        (const __attribute__((address_space(1))) unsigned*)g,
        (__attribute__((address_space(3))) unsigned*)l, 16, 0, 0);
}

// ---------------------------------------------------------------------------
// weights fp32->fp16 + zero atomic accumulators (ctx_raw+ksum+lnacc = 37888)
__global__ __launch_bounds__(256) void prep_kernel(
    const float* __restrict__ qkv_w, const float* __restrict__ conv_w,
    _Float16* __restrict__ wh, _Float16* __restrict__ ch, float* __restrict__ zbuf)
{
    int i = blockIdx.x * 256 + threadIdx.x;       // 0..131071
    if (i < 98304) wh[i] = (_Float16)qkv_w[i];
    else           ch[i - 98304] = (_Float16)conv_w[i - 98304];
    if (i < 37888) zbuf[i] = 0.f;
}

// ---------------------------------------------------------------------------
// Fused transpose + QKV GEMM: C[b][o][n] = sum_c W[o][c] * x[b][c][n]
// A (wh) fp16 k-contiguous; B is raw fp32 x in [c][n], staged LINEARLY via
// global_load_lds (no swizzle needed). B-fragment column remap: fragment j,
// lane l16 covers col nw + l16*4 + j, so one ds_read_b128 (4 consecutive
// fp32) feeds element kk of all 4 fragments -> 8 b128 reads/thread/K-step,
// conflict-free. Output column permutation absorbed by the LDS epilogue.
// 2-phase double-buffered prefetch: stage tile k+1 before computing tile k
// so the end-of-step barrier drain overlaps HBM latency with compute.
__global__ __launch_bounds__(256) void gemm_qkv(
    const _Float16* __restrict__ A,    // [384][256] fp16
    const float* __restrict__ X,       // [b][256][16384] fp32
    _Float16* __restrict__ Cm)         // [b][384][16384]
{
    __shared__ _Float16 smem[24576];   // 2 x (As 8KB | Xs 16KB) ; Cs 32KB reuse
    const int t  = threadIdx.x;
    const int b  = blockIdx.x;
    const int m0 = blockIdx.y * 128;
    const int n0 = blockIdx.z * 128;
    const float* Xb = X + (long)b * DIMC * NPIX;
    const int w = t >> 6, lane = t & 63;
    const int q = lane >> 4, l16 = lane & 15;
    const int mw = (w >> 1) * 64, nw = (w & 1) * 64;

    f32x4 acc[4][4] = {};

    // stage K-tile k0 into buffer buf (As: 128x32 fp16, Xs: 32x128 fp32)
    auto STAGE = [&](int buf, int k0) {
        _Float16* As = smem + buf * 12288;
        float*    Xs = (float*)(smem + buf * 12288 + 4096);
        #pragma unroll
        for (int is = 0; is < 2; is++) {
            int idx = is * 256 + t;               // 0..511
            int row = idx >> 2, kc = (idx & 3) * 8;
            gl_lds16(&A[(long)(m0 + row) * DIMC + k0 + kc], &As[idx * 8]);
        }
        #pragma unroll
        for (int is = 0; is < 4; is++) {
            int idx = is * 256 + t;               // 0..1023
            int c = idx >> 5, f4 = (idx & 31) * 4;
            gl_lds16(&Xb[(long)(k0 + c) * NPIX + n0 + f4], &Xs[c * 128 + f4]);
        }
    };

    STAGE(0, 0);
    __syncthreads();                               // vmcnt(0) drain + barrier
    int cur = 0;

    for (int kt = 0; kt < 8; kt++) {
        if (kt < 7) STAGE(cur ^ 1, (kt + 1) * 32);   // prefetch next tile

        const _Float16* As = smem + cur * 12288;
        const float*    Xs = (const float*)(smem + cur * 12288 + 4096);

        f16x8 af[4], bf[4];
        #pragma unroll
        for (int i = 0; i < 4; i++)
            af[i] = *(const f16x8*)&As[(mw + i * 16 + l16) * 32 + q * 8];
        #pragma unroll
        for (int kk = 0; kk < 8; kk++) {
            f32x4 xv = *(const f32x4*)&Xs[(q * 8 + kk) * 128 + nw + l16 * 4];
            bf[0][kk] = (_Float16)xv[0];
            bf[1][kk] = (_Float16)xv[1];
            bf[2][kk] = (_Float16)xv[2];
            bf[3][kk] = (_Float16)xv[3];
        }
        #pragma unroll
        for (int i = 0; i < 4; i++)
            #pragma unroll
            for (int j = 0; j < 4; j++)
                acc[i][j] = __builtin_amdgcn_mfma_f32_16x16x32_f16(af[i], bf[j], acc[i][j], 0, 0, 0);

        __syncthreads();                           // drains prefetch vmcnt + WAR
        cur ^= 1;
    }

    // ---- epilogue: acc -> swizzled LDS (b64 packed) -> coalesced global ----
    // lane (q,l16) acc[i][j][r] holds C[mw+i*16+q*4+r][nw+l16*4+j]
    _Float16* Cs = smem;
    #pragma unroll
    for (int i = 0; i < 4; i++) {
        #pragma unroll
        for (int r = 0; r < 4; r++) {
            int row = mw + i * 16 + q * 4 + r;
            int col = nw + l16 * 4;
            f16x4 h4;
            h4[0] = (_Float16)acc[i][0][r];
            h4[1] = (_Float16)acc[i][1][r];
            h4[2] = (_Float16)acc[i][2][r];
            h4[3] = (_Float16)acc[i][3][r];
            *(f16x4*)&Cs[row * 128 + (col ^ ((row & 15) << 3))] = h4;
        }
    }
    __syncthreads();
    _Float16* Cb = Cm + (long)b * ((long)OQKV * NPIX);
    #pragma unroll
    for (int it = 0; it < 8; it++) {
        int u = it * 256 + t;                  // 0..2047
        int row = u >> 4, cg = u & 15;
        f16x8 v8 = *(const f16x8*)&Cs[row * 128 + ((cg * 8) ^ ((row & 15) << 3))];
        *(f16x8*)&Cb[(long)(m0 + row) * NPIX + n0 + cg * 8] = v8;
    }
}

// ---------------------------------------------------------------------------
// MFMA fp16 GEMM: C[b][m][n] = sum_k A[m][k] * B[b][n][k]   (both k-contiguous)
// 128x128 tile, BK=32, 256 threads (4 waves, 64x64 each), 16x16x32 MFMA.
// Epilogue: XOR-swizzled LDS C-tile -> coalesced f16x8 stores. EPI=1: also
// accumulate per-row sum/sumsq into lnacc via atomics.
template<int K, int EPI>
__global__ __launch_bounds__(256) void gemm_h(
    const _Float16* __restrict__ A,    // [M][K]
    const _Float16* __restrict__ Bm,   // [b][N][K]
    _Float16* __restrict__ Cm,         // [b][M][NPIX]
    long bsB, long bsC, float* __restrict__ lnacc)
{
    __shared__ _Float16 smem[16384];   // As 8KB | Bs 8KB ; reused as Cs 32KB
    _Float16* As = smem;
    _Float16* Bs = smem + 4096;
    const int t  = threadIdx.x;
    const int b  = blockIdx.x;
    const int m0 = blockIdx.y * 128;
    const int n0 = blockIdx.z * 128;
    const _Float16* Bb = Bm + (long)b * bsB;
    const int w = t >> 6, lane = t & 63;
    const int q = lane >> 4, l16 = lane & 15;
    const int mw = (w >> 1) * 64, nw = (w & 1) * 64;

    f32x4 acc[4][4] = {};

    for (int k0 = 0; k0 < K; k0 += 32) {
        #pragma unroll
        for (int is = 0; is < 2; is++) {
            int idx = is * 256 + t;               // 0..511
            int row = idx >> 2, kc = (idx & 3) * 8;
            gl_lds16(&A [(long)(m0 + row) * K + k0 + kc], &As[idx * 8]);
            gl_lds16(&Bb[(long)(n0 + row) * K + k0 + kc], &Bs[idx * 8]);
        }
        __syncthreads();
        f16x8 af[4], bf[4];
        #pragma unroll
        for (int i = 0; i < 4; i++) {
            af[i] = *(const f16x8*)&As[(mw + i * 16 + l16) * 32 + q * 8];
            bf[i] = *(const f16x8*)&Bs[(nw + i * 16 + l16) * 32 + q * 8];
        }
        #pragma unroll
        for (int i = 0; i < 4; i++)
            #pragma unroll
            for (int j = 0; j < 4; j++)
                acc[i][j] = __builtin_amdgcn_mfma_f32_16x16x32_f16(af[i], bf[j], acc[i][j], 0, 0, 0);
        __syncthreads();
    }

    // ---- epilogue: acc -> swizzled LDS -> coalesced global ----
    _Float16* Cs = smem;
    #pragma unroll
    for (int i = 0; i < 4; i++) {
        #pragma unroll
        for (int j = 0; j < 4; j++) {
            #pragma unroll
            for (int r = 0; r < 4; r++) {
                int row = mw + i * 16 + q * 4 + r;
                int col = nw + j * 16 + l16;
                Cs[row * 128 + (col ^ ((row & 15) << 3))] = (_Float16)acc[i][j][r];
            }
        }
    }
    __syncthreads();
    _Float16* Cb = Cm + (long)b * bsC;
    #pragma unroll
    for (int it = 0; it < 8; it++) {
        int u = it * 256 + t;                  // 0..2047
        int row = u >> 4, cg = u & 15;
        f16x8 v8 = *(const f16x8*)&Cs[row * 128 + ((cg * 8) ^ ((row & 15) << 3))];
        *(f16x8*)&Cb[(long)(m0 + row) * NPIX + n0 + cg * 8] = v8;
        if (EPI) {
            float s = 0.f, sq = 0.f;
            #pragma unroll
            for (int k = 0; k < 8; k++) { float f = (float)v8[k]; s += f; sq += f * f; }
            #pragma unroll
            for (int off = 8; off > 0; off >>= 1) {
                s  += __shfl_down(s,  off, 16);
                sq += __shfl_down(sq, off, 16);
            }
            if ((t & 15) == 0) {
                int rg = b * DIMC + m0 + row;
                atomicAdd(&lnacc[rg * 2],     s);
                atomicAdd(&lnacc[rg * 2 + 1], sq);
            }
        }
    }
}

// ---------------------------------------------------------------------------
// MFMA context: ctx_raw[bh][d][e] += sum_n exp(k[d,n]) * v[e,n]
//               ksum[bh][d]       += sum_n exp(k[d,n])
// No max-subtraction: k ~ N(0,1), exp safe in fp32; softmax shift-invariant.
// grid (8 chunks, 32 bh), 4 waves/block each covering 512 n.
__global__ __launch_bounds__(256) void ctx_mfma(const _Float16* __restrict__ qkvh,
    float* __restrict__ ctx_raw, float* __restrict__ ksum)
{
    __shared__ float cbuf[4][1024];
    int t = threadIdx.x;
    int w = t >> 6, lane = t & 63;
    int q = lane >> 4, l16 = lane & 15;
    int bh = blockIdx.y, b = bh >> 2, h = bh & 3;
    const _Float16* kb = qkvh + ((long)b * OQKV + HID + h * DHEAD) * NPIX;
    const _Float16* vb = qkvh + ((long)b * OQKV + 2 * HID + h * DHEAD) * NPIX;
    long n0 = (long)blockIdx.x * 2048 + w * 512 + q * 8;

    f32x4 c00 = {}, c01 = {}, c10 = {}, c11 = {};
    float ks0 = 0.f, ks1 = 0.f;

    for (int s = 0; s < 16; s++) {
        long n = n0 + s * 32;
        f16x8 kf0 = *(const f16x8*)&kb[(long)l16 * NPIX + n];
        f16x8 kf1 = *(const f16x8*)&kb[(long)(16 + l16) * NPIX + n];
        f16x8 vf0 = *(const f16x8*)&vb[(long)l16 * NPIX + n];
        f16x8 vf1 = *(const f16x8*)&vb[(long)(16 + l16) * NPIX + n];
        f16x8 e0, e1;
        #pragma unroll
        for (int j = 0; j < 8; j++) {
            float ea = __expf((float)kf0[j]); e0[j] = (_Float16)ea; ks0 += ea;
            float eb = __expf((float)kf1[j]); e1[j] = (_Float16)eb; ks1 += eb;
        }
        c00 = __builtin_amdgcn_mfma_f32_16x16x32_f16(e0, vf0, c00, 0, 0, 0);
        c01 = __builtin_amdgcn_mfma_f32_16x16x32_f16(e0, vf1, c01, 0, 0, 0);
        c10 = __builtin_amdgcn_mfma_f32_16x16x32_f16(e1, vf0, c10, 0, 0, 0);
        c11 = __builtin_amdgcn_mfma_f32_16x16x32_f16(e1, vf1, c11, 0, 0, 0);
    }

    // ksum: reduce across q-groups (lanes l16, +16, +32, +48)
    ks0 += __shfl_down(ks0, 32); ks0 += __shfl_down(ks0, 16);
    ks1 += __shfl_down(ks1, 32); ks1 += __shfl_down(ks1, 16);
    if (lane < 16) {
        atomicAdd(&ksum[bh * DHEAD + l16],      ks0);
        atomicAdd(&ksum[bh * DHEAD + 16 + l16], ks1);
    }

    // ctx: combine 4 waves via LDS, one atomicAdd per entry
    float* cb = cbuf[w];
    #pragma unroll
    for (int r = 0; r < 4; r++) {
        cb[(q * 4 + r) * 32 + l16]            = c00[r];
        cb[(q * 4 + r) * 32 + 16 + l16]       = c01[r];
        cb[(16 + q * 4 + r) * 32 + l16]       = c10[r];
        cb[(16 + q * 4 + r) * 32 + 16 + l16]  = c11[r];
    }
    __syncthreads();
    #pragma unroll
    for (int ii = 0; ii < 4; ii++) {
        int idx = ii * 256 + t;
        float s = cbuf[0][idx] + cbuf[1][idx] + cbuf[2][idx] + cbuf[3][idx];
        atomicAdd(&ctx_raw[(long)bh * 1024 + idx], s);
    }
}

// ---------------------------------------------------------------------------
// q-softmax + out' = N*out = (SCALE*ctx_raw/ksum) @ qsm, written into the
// dead v-region as [b][n][e] fp16 (k-contiguous for the conv GEMM).
__global__ __launch_bounds__(256) void outq_h(_Float16* __restrict__ qkvh,
    const float* __restrict__ ctx_raw, const float* __restrict__ ksum)
{
    __shared__ float ctx_t[4][32][32];   // [h][e][d]
    int tid = threadIdx.x;
    int n = blockIdx.x * 256 + tid;
    int b = blockIdx.y;
    #pragma unroll
    for (int i = 0; i < 16; i++) {
        int idx = i * 256 + tid;           // 0..4095
        int h = idx >> 10, de = idx & 1023;
        int d = de >> 5, e = de & 31;
        float s = ksum[(b * 4 + h) * DHEAD + d];
        ctx_t[h][e][d] = SCALE * ctx_raw[(long)(b * 4 + h) * 1024 + de] / s;
    }
    __syncthreads();
    _Float16* ob = qkvh + ((long)b * OQKV + 2 * HID) * NPIX + (long)n * HID;
    for (int h = 0; h < 4; h++) {
        const _Float16* qb = qkvh + ((long)b * OQKV + h * DHEAD) * NPIX + n;
        float qv[32];
        float mx = -1e30f;
        #pragma unroll
        for (int e = 0; e < 32; e++) { qv[e] = (float)qb[(long)e * NPIX]; mx = fmaxf(mx, qv[e]); }
        float s = 0.f;
        #pragma unroll
        for (int e = 0; e < 32; e++) { qv[e] = __expf(qv[e] - mx); s += qv[e]; }
        float qs = 1.f / s;
        float4 o4[8];
        #pragma unroll
        for (int j = 0; j < 8; j++) o4[j] = make_float4(0,0,0,0);
        #pragma unroll 8
        for (int e = 0; e < 32; e++) {
            float qe = qv[e] * qs;
            #pragma unroll
            for (int j = 0; j < 8; j++) {
                float4 c = *(const float4*)&ctx_t[h][e][j * 4];
                o4[j].x += c.x * qe; o4[j].y += c.y * qe;
                o4[j].z += c.z * qe; o4[j].w += c.w * qe;
            }
        }
        #pragma unroll
        for (int j = 0; j < 4; j++) {
            f16x8 pk;
            float4 a = o4[j * 2], bb = o4[j * 2 + 1];
            pk[0] = (_Float16)a.x;  pk[1] = (_Float16)a.y;
            pk[2] = (_Float16)a.z;  pk[3] = (_Float16)a.w;
            pk[4] = (_Float16)bb.x; pk[5] = (_Float16)bb.y;
            pk[6] = (_Float16)bb.z; pk[7] = (_Float16)bb.w;
            *(f16x8*)&ob[h * DHEAD + j * 8] = pk;
        }
    }
}

// ---------------------------------------------------------------------------
// finalize LN coefficients from the fused sums (y' = N*y scale)
__global__ __launch_bounds__(256) void ln_finalize(const float* __restrict__ lnacc,
    const float* __restrict__ gamma, const float* __restrict__ beta,
    float* __restrict__ mv)
{
    int row = blockIdx.x * 256 + threadIdx.x;     // 0..2047
    float s = lnacc[row * 2], sq = lnacc[row * 2 + 1];
    float meanp = s * (1.f / NPIX);
    float varp  = fmaxf(sq * (1.f / NPIX) - meanp * meanp, 0.f);
    float rinv  = rsqrtf(varp * (1.f / ((float)NPIX * (float)NPIX)) + EPS);
    int c = row & 255;
    float g = rinv * gamma[c];
    mv[row * 2]     = g * (1.f / NPIX);
    mv[row * 2 + 1] = beta[c] - meanp * (1.f / NPIX) * g;
}

// ---------------------------------------------------------------------------
// out = y' * a + be   (fp16 in, fp32 out)
__global__ __launch_bounds__(256) void ln_apply(const _Float16* __restrict__ yh,
    const float* __restrict__ mv, float* __restrict__ out)
{
    long i8 = (long)blockIdx.x * 256 + threadIdx.x;   // f16x8 index
    int row = (int)(i8 >> 11);                        // 2048 vec8 per row
    float a = mv[row * 2], be = mv[row * 2 + 1];
    f16x8 v = *(const f16x8*)&yh[i8 * 8];
    float4 o1, o2;
    o1.x = (float)v[0] * a + be; o1.y = (float)v[1] * a + be;
    o1.z = (float)v[2] * a + be; o1.w = (float)v[3] * a + be;
    o2.x = (float)v[4] * a + be; o2.y = (float)v[5] * a + be;
    o2.z = (float)v[6] * a + be; o2.w = (float)v[7] * a + be;
    *(float4*)&out[i8 * 8]     = o1;
    *(float4*)&out[i8 * 8 + 4] = o2;
}

// ---------------------------------------------------------------------------
extern "C" void kernel_launch(void* const* d_in, const int* in_sizes, int n_in,
                              void* d_out, int out_size, void* d_ws, size_t ws_size,
                              hipStream_t stream)
{
    const float* x      = (const float*)d_in[0];
    const float* qkv_w  = (const float*)d_in[1];
    const float* conv_w = (const float*)d_in[2];
    const float* gamma  = (const float*)d_in[4];
    const float* beta   = (const float*)d_in[5];
    float* out = (float*)d_out;

    _Float16* yh   = (_Float16*)d_ws;                 // 33,554,432 h (conv output)
    _Float16* qkvh = yh + 33554432;                   // 50,331,648 h
    _Float16* wh   = qkvh + 50331648;                 // 98,304 h
    _Float16* ch   = wh + 98304;                      // 32,768 h
    float* ctx_raw = (float*)(ch + 32768);            // 32,768
    float* ksum    = ctx_raw + 32768;                 // 1,024
    float* lnacc   = ksum + 1024;                     // 4,096
    float* mv      = lnacc + 4096;                    // 4,096

    prep_kernel<<<512, 256, 0, stream>>>(qkv_w, conv_w, wh, ch, ctx_raw);
    gemm_qkv<<<dim3(BATCH, 3, 128), 256, 0, stream>>>(wh, x, qkvh);
    ctx_mfma<<<dim3(8, 32), 256, 0, stream>>>(qkvh, ctx_raw, ksum);
    outq_h<<<dim3(64, BATCH), 256, 0, stream>>>(qkvh, ctx_raw, ksum);
    gemm_h<128, 1><<<dim3(BATCH, 2, 128), 256, 0, stream>>>(
        ch, qkvh + (long)2 * HID * NPIX, yh, (long)OQKV * NPIX, (long)DIMC * NPIX, lnacc);
    ln_finalize<<<8, 256, 0, stream>>>(lnacc, gamma, beta, mv);
    ln_apply<<<16384, 256, 0, stream>>>(yh, mv, out);
}